// Round 5
// baseline (150.332 us; speedup 1.0000x reference)
//
#include <hip/hip_runtime.h>
#include <hip/hip_bf16.h>
#include <math.h>

// x: (B=16, S=512, T=64, F=256) fp32.  rows = B*S = 8192, tile = T*F = 16384 floats.
// out[row][f] = sum_t softmax_t( sum_f' x[row][t][f'] * wq[row][f'] ) * x[row][t][f]
// wq[row][f]  = sum_d W[f][d] * x[row][63][d]

#define TT 64
#define FF 256
#define QR2 16  // rows per block in wq kernel v2

// ---------------- kernel 0: Wt = W^T (tiny, L2-resident afterwards) ----------------
__global__ __launch_bounds__(256) void wt_kernel(const float* __restrict__ W,
                                                 float* __restrict__ Wt) {
    __shared__ float t[32][33];
    const int bx = blockIdx.x & 7;    // d-tile
    const int by = blockIdx.x >> 3;   // f-tile
    const int lx = threadIdx.x & 31;
    const int ly = threadIdx.x >> 5;  // 0..7
#pragma unroll
    for (int i = 0; i < 4; ++i)
        t[ly + i * 8][lx] = W[(size_t)(by * 32 + ly + i * 8) * FF + bx * 32 + lx];
    __syncthreads();
#pragma unroll
    for (int i = 0; i < 4; ++i)
        Wt[(size_t)(bx * 32 + ly + i * 8) * FF + by * 32 + lx] = t[lx][ly + i * 8];
}

// ---------------- kernel 1: wq = W @ q, coalesced Wt + LDS q broadcast ----------------
// lane l owns f = 4l..4l+3 (full F covered by one wave); wave w handles 4 q-rows.
// Per d-chunk: 4 coalesced b128 Wt loads + 4 broadcast b128 LDS reads + 64 FMA.
__global__ __launch_bounds__(256) void wq_kernel2(const float* __restrict__ x,
                                                  const float* __restrict__ Wt,
                                                  float* __restrict__ wq) {
    __shared__ float qs[QR2][FF];
    const int tid = threadIdx.x;
    const int r0  = blockIdx.x * QR2;

    // stage QR2 query rows (last timestep of each tile), coalesced float4
    for (int i = tid; i < QR2 * (FF / 4); i += 256) {
        int g = i >> 6;         // row within block
        int c = i & 63;         // float4 index
        float4 v = *reinterpret_cast<const float4*>(
            x + (size_t)(r0 + g) * (TT * FF) + (size_t)(TT - 1) * FF + 4 * c);
        *reinterpret_cast<float4*>(&qs[g][4 * c]) = v;
    }
    __syncthreads();

    const int w = tid >> 6;     // wave: rows 4w..4w+3
    const int l = tid & 63;     // f = 4l..4l+3

    float4 acc[4];
#pragma unroll
    for (int g = 0; g < 4; ++g) acc[g] = make_float4(0.f, 0.f, 0.f, 0.f);

    for (int d0 = 0; d0 < FF; d0 += 4) {
        float4 w0 = *reinterpret_cast<const float4*>(Wt + (size_t)(d0 + 0) * FF + 4 * l);
        float4 w1 = *reinterpret_cast<const float4*>(Wt + (size_t)(d0 + 1) * FF + 4 * l);
        float4 w2 = *reinterpret_cast<const float4*>(Wt + (size_t)(d0 + 2) * FF + 4 * l);
        float4 w3 = *reinterpret_cast<const float4*>(Wt + (size_t)(d0 + 3) * FF + 4 * l);
#pragma unroll
        for (int g = 0; g < 4; ++g) {
            float4 qv = *reinterpret_cast<const float4*>(&qs[w * 4 + g][d0]);  // broadcast
            acc[g].x += qv.x * w0.x + qv.y * w1.x + qv.z * w2.x + qv.w * w3.x;
            acc[g].y += qv.x * w0.y + qv.y * w1.y + qv.z * w2.y + qv.w * w3.y;
            acc[g].z += qv.x * w0.z + qv.y * w1.z + qv.z * w2.z + qv.w * w3.z;
            acc[g].w += qv.x * w0.w + qv.y * w1.w + qv.z * w2.w + qv.w * w3.w;
        }
    }
#pragma unroll
    for (int g = 0; g < 4; ++g)
        *reinterpret_cast<float4*>(wq + (size_t)(r0 + w * 4 + g) * FF + 4 * l) = acc[g];
}

// ---------------- core per-row attention (R2 measured-best version, verbatim) ----------------
__device__ __forceinline__ void attn_row(const float* __restrict__ xt,
                                         float4 wqv,
                                         float* __restrict__ out_row,
                                         int tid) {
    const int lane = tid & 63;
    const int w    = tid >> 6;   // wave 0..3, owns t = 16w .. 16w+15

    __shared__ float sc[TT];
    __shared__ float mbuf[4];
    __shared__ float lbuf[4];
    __shared__ float part[4][FF];

    float4 xv[16];
#pragma unroll
    for (int j = 0; j < 16; ++j)
        xv[j] = *reinterpret_cast<const float4*>(
            xt + (size_t)(w * 16 + j) * FF + 4 * lane);

    float p[16];
#pragma unroll
    for (int j = 0; j < 16; ++j)
        p[j] = xv[j].x * wqv.x + xv[j].y * wqv.y + xv[j].z * wqv.z + xv[j].w * wqv.w;

    // fold-reduce: 16 row-sums across 64 lanes in 17 shuffles
    const bool b5 = (lane & 32) != 0;
    const bool b4 = (lane & 16) != 0;
    const bool b3 = (lane & 8) != 0;
    const bool b2 = (lane & 4) != 0;

    float s8[8];
#pragma unroll
    for (int j = 0; j < 8; ++j) {
        float send = b5 ? p[j] : p[j + 8];
        float recv = __shfl_xor(send, 32, 64);
        s8[j] = (b5 ? p[j + 8] : p[j]) + recv;
    }
    float s4[4];
#pragma unroll
    for (int j = 0; j < 4; ++j) {
        float send = b4 ? s8[j] : s8[j + 4];
        float recv = __shfl_xor(send, 16, 64);
        s4[j] = (b4 ? s8[j + 4] : s8[j]) + recv;
    }
    float s2[2];
#pragma unroll
    for (int j = 0; j < 2; ++j) {
        float send = b3 ? s4[j] : s4[j + 2];
        float recv = __shfl_xor(send, 8, 64);
        s2[j] = (b3 ? s4[j + 2] : s4[j]) + recv;
    }
    {
        float send = b2 ? s2[0] : s2[1];
        float recv = __shfl_xor(send, 4, 64);
        s2[0] = (b2 ? s2[1] : s2[0]) + recv;
    }
    float y = s2[0];
    y += __shfl_xor(y, 2, 64);
    y += __shfl_xor(y, 1, 64);          // full score of row (lane>>2)&15

    float mw = y;
    mw = fmaxf(mw, __shfl_xor(mw, 4, 64));
    mw = fmaxf(mw, __shfl_xor(mw, 8, 64));
    mw = fmaxf(mw, __shfl_xor(mw, 16, 64));
    mw = fmaxf(mw, __shfl_xor(mw, 32, 64));

    if ((lane & 3) == 0) sc[w * 16 + (lane >> 2)] = y;
    if (lane == 0) mbuf[w] = mw;
    __syncthreads();

    float m = fmaxf(fmaxf(mbuf[0], mbuf[1]), fmaxf(mbuf[2], mbuf[3]));

    float wt[16];
    float lw = 0.f;
#pragma unroll
    for (int j = 0; j < 16; ++j) {
        wt[j] = __expf(sc[w * 16 + j] - m);
        lw += wt[j];
    }

    float4 acc = make_float4(0.f, 0.f, 0.f, 0.f);
#pragma unroll
    for (int j = 0; j < 16; ++j) {
        acc.x += wt[j] * xv[j].x;
        acc.y += wt[j] * xv[j].y;
        acc.z += wt[j] * xv[j].z;
        acc.w += wt[j] * xv[j].w;
    }
    *reinterpret_cast<float4*>(&part[w][4 * lane]) = acc;
    if (lane == 0) lbuf[w] = lw;
    __syncthreads();

    float l = lbuf[0] + lbuf[1] + lbuf[2] + lbuf[3];
    float v = part[0][tid] + part[1][tid] + part[2][tid] + part[3][tid];
    out_row[tid] = v / l;
}

__global__ __launch_bounds__(256) void attn_kernel(const float* __restrict__ x,
                                                   const float* __restrict__ wq,
                                                   float* __restrict__ out) {
    const int row = blockIdx.x;
    const int tid = threadIdx.x;
    const int lane = tid & 63;
    const float* xt = x + (size_t)row * (TT * FF);

    float4 wqv = *reinterpret_cast<const float4*>(wq + (size_t)row * FF + 4 * lane);
    attn_row(xt, wqv, out + (size_t)row * FF, tid);
}

// ---------------- fallback: fully fused (only if ws too small) ----------------
__global__ __launch_bounds__(256) void fused_kernel(const float* __restrict__ x,
                                                    const float* __restrict__ W,
                                                    float* __restrict__ out) {
    const int row = blockIdx.x;
    const int tid = threadIdx.x;
    const int lane = tid & 63;
    const float* xt = x + (size_t)row * (TT * FF);

    __shared__ float q[FF];
    __shared__ float wqs[FF];
    if (tid < 64) {
        float4 v = *reinterpret_cast<const float4*>(xt + (size_t)(TT - 1) * FF + tid * 4);
        *reinterpret_cast<float4*>(&q[tid * 4]) = v;
    }
    __syncthreads();

    float a = 0.f;
    const float* wrow = W + (size_t)tid * FF;
    for (int d0 = 0; d0 < FF; d0 += 4) {
        float4 wv = *reinterpret_cast<const float4*>(wrow + d0);
        float4 qv = *reinterpret_cast<const float4*>(&q[d0]);
        a += wv.x * qv.x + wv.y * qv.y + wv.z * qv.z + wv.w * qv.w;
    }
    wqs[tid] = a;
    __syncthreads();

    float4 wqv = *reinterpret_cast<const float4*>(&wqs[4 * lane]);
    attn_row(xt, wqv, out + (size_t)row * FF, tid);
}

extern "C" void kernel_launch(void* const* d_in, const int* in_sizes, int n_in,
                              void* d_out, int out_size, void* d_ws, size_t ws_size,
                              hipStream_t stream) {
    (void)n_in; (void)out_size;
    const float* x = (const float*)d_in[0];
    const float* W = (const float*)d_in[1];
    float* out = (float*)d_out;

    const int rows = in_sizes[0] / (TT * FF);   // 8192
    const size_t wq_bytes = (size_t)rows * FF * sizeof(float);
    const size_t wt_bytes = (size_t)FF * FF * sizeof(float);

    if (ws_size >= wq_bytes + wt_bytes) {
        float* wq = (float*)d_ws;
        float* Wt = (float*)((char*)d_ws + wq_bytes);
        wt_kernel<<<64, 256, 0, stream>>>(W, Wt);
        wq_kernel2<<<rows / QR2, 256, 0, stream>>>(x, Wt, wq);
        attn_kernel<<<rows, 256, 0, stream>>>(x, wq, out);
    } else {
        fused_kernel<<<rows, 256, 0, stream>>>(x, W, out);
    }
}

// Round 6
// 141.706 us; speedup vs baseline: 1.0609x; 1.0609x over previous
//
#include <hip/hip_runtime.h>
#include <hip/hip_bf16.h>
#include <math.h>

// x: (B=16, S=512, T=64, F=256) fp32.  rows = B*S = 8192, tile = T*F = 16384 floats.
// out[row][f] = sum_t softmax_t( sum_f' x[row][t][f'] * wq[row][f'] ) * x[row][t][f]
// wq[row][f]  = sum_d W[f][d] * x[row][63][d]

#define TT 64
#define FF 256
#define QR 8    // query rows per block in wq kernel

// ---------------- kernel 1: wq = W @ q (R2 measured-best version, verbatim) ----------------
__global__ __launch_bounds__(256) void wq_kernel(const float* __restrict__ x,
                                                 const float* __restrict__ W,
                                                 float* __restrict__ wq) {
    __shared__ float q[QR][FF];
    const int tid = threadIdx.x;
    const int r0  = blockIdx.x * QR;

    for (int i = tid; i < QR * (FF / 4); i += 256) {
        int g  = i >> 6;
        int d4 = i & 63;
        float4 v = *reinterpret_cast<const float4*>(
            x + (size_t)(r0 + g) * (TT * FF) + (size_t)(TT - 1) * FF + d4 * 4);
        *reinterpret_cast<float4*>(&q[g][d4 * 4]) = v;
    }
    __syncthreads();

    const int f = tid;
    float acc[QR];
#pragma unroll
    for (int g = 0; g < QR; ++g) acc[g] = 0.f;

    const float* wrow = W + (size_t)f * FF;
    for (int d0 = 0; d0 < FF; d0 += 4) {
        float4 wv = *reinterpret_cast<const float4*>(wrow + d0);
#pragma unroll
        for (int g = 0; g < QR; ++g) {
            float4 qv = *reinterpret_cast<const float4*>(&q[g][d0]);  // broadcast, conflict-free
            acc[g] += wv.x * qv.x + wv.y * qv.y + wv.z * qv.z + wv.w * qv.w;
        }
    }
#pragma unroll
    for (int g = 0; g < QR; ++g)
        wq[(size_t)(r0 + g) * FF + f] = acc[g];
}

// ---------------- kernel 2: attention, 512 threads = 8 waves x 8 t-rows ----------------
// Halved per-wave register footprint (xv[8]=32 VGPR) to cross the 128-VGPR
// occupancy boundary: 16 waves/CU instead of 8. Same algorithm as R2-best.
__global__ __launch_bounds__(512, 4) void attn_kernel8(const float* __restrict__ x,
                                                       const float* __restrict__ wq,
                                                       float* __restrict__ out) {
    const int tid  = threadIdx.x;
    const int lane = tid & 63;
    const int w    = tid >> 6;        // wave 0..7, owns t = 8w .. 8w+7
    const int row  = blockIdx.x;
    const float* xt = x + (size_t)row * (TT * FF);

    __shared__ float sc[TT];
    __shared__ float mbuf[8];
    __shared__ float lbuf[8];
    __shared__ float part[8][FF];

    float4 wqv = *reinterpret_cast<const float4*>(wq + (size_t)row * FF + 4 * lane);

    // 8 rows in registers: lane holds f = 4l..4l+3 of each (coalesced 1KB/row)
    float4 xv[8];
#pragma unroll
    for (int j = 0; j < 8; ++j)
        xv[j] = *reinterpret_cast<const float4*>(
            xt + (size_t)(w * 8 + j) * FF + 4 * lane);

    float p[8];
#pragma unroll
    for (int j = 0; j < 8; ++j)
        p[j] = xv[j].x * wqv.x + xv[j].y * wqv.y + xv[j].z * wqv.z + xv[j].w * wqv.w;

    // fold-reduce: 8 row-sums across 64 lanes in 10 shuffles
    const bool b5 = (lane & 32) != 0;
    const bool b4 = (lane & 16) != 0;
    const bool b3 = (lane & 8) != 0;

    float s4[4];
#pragma unroll
    for (int j = 0; j < 4; ++j) {
        float send = b5 ? p[j] : p[j + 4];
        float recv = __shfl_xor(send, 32, 64);
        s4[j] = (b5 ? p[j + 4] : p[j]) + recv;      // row = 4*b5 + j
    }
    float s2[2];
#pragma unroll
    for (int j = 0; j < 2; ++j) {
        float send = b4 ? s4[j] : s4[j + 2];
        float recv = __shfl_xor(send, 16, 64);
        s2[j] = (b4 ? s4[j + 2] : s4[j]) + recv;    // row = 4*b5 + 2*b4 + j
    }
    {
        float send = b3 ? s2[0] : s2[1];
        float recv = __shfl_xor(send, 8, 64);
        s2[0] = (b3 ? s2[1] : s2[0]) + recv;        // row = lane>>3
    }
    float y = s2[0];
    y += __shfl_xor(y, 4, 64);
    y += __shfl_xor(y, 2, 64);
    y += __shfl_xor(y, 1, 64);                      // full score of row lane>>3

    // wave max over its 8 rows (fold lane bits 3..5)
    float mw = y;
    mw = fmaxf(mw, __shfl_xor(mw, 8, 64));
    mw = fmaxf(mw, __shfl_xor(mw, 16, 64));
    mw = fmaxf(mw, __shfl_xor(mw, 32, 64));

    if ((lane & 7) == 0) sc[w * 8 + (lane >> 3)] = y;
    if (lane == 0) mbuf[w] = mw;
    __syncthreads();

    float m = mbuf[0];
#pragma unroll
    for (int i = 1; i < 8; ++i) m = fmaxf(m, mbuf[i]);

    float wt[8];
    float lw = 0.f;
#pragma unroll
    for (int j = 0; j < 8; ++j) {
        wt[j] = __expf(sc[w * 8 + j] - m);
        lw += wt[j];
    }

    float4 acc = make_float4(0.f, 0.f, 0.f, 0.f);
#pragma unroll
    for (int j = 0; j < 8; ++j) {
        acc.x += wt[j] * xv[j].x;
        acc.y += wt[j] * xv[j].y;
        acc.z += wt[j] * xv[j].z;
        acc.w += wt[j] * xv[j].w;
    }
    *reinterpret_cast<float4*>(&part[w][4 * lane]) = acc;
    if (lane == 0) lbuf[w] = lw;
    __syncthreads();

    if (tid < FF) {
        float l = 0.f;
#pragma unroll
        for (int i = 0; i < 8; ++i) l += lbuf[i];
        float v = 0.f;
#pragma unroll
        for (int i = 0; i < 8; ++i) v += part[i][tid];
        out[(size_t)row * FF + tid] = v / l;
    }
}

// ---------------- fallback: fully fused (only if ws too small) ----------------
__device__ __forceinline__ void attn_row_fb(const float* __restrict__ xt,
                                            float4 wqv,
                                            float* __restrict__ out_row,
                                            int tid) {
    const int lane = tid & 63;
    const int w    = tid >> 6;

    __shared__ float sc[TT];
    __shared__ float part[4][FF];

    float4 xv[16];
#pragma unroll
    for (int j = 0; j < 16; ++j)
        xv[j] = *reinterpret_cast<const float4*>(xt + (size_t)(w * 16 + j) * FF + 4 * lane);

#pragma unroll
    for (int j = 0; j < 16; ++j) {
        float s = xv[j].x * wqv.x + xv[j].y * wqv.y + xv[j].z * wqv.z + xv[j].w * wqv.w;
#pragma unroll
        for (int off = 32; off > 0; off >>= 1)
            s += __shfl_xor(s, off, 64);
        if (lane == 0) sc[w * 16 + j] = s;
    }
    __syncthreads();

    float m = -INFINITY;
#pragma unroll
    for (int t = 0; t < TT; ++t) m = fmaxf(m, sc[t]);
    float l = 0.f;
#pragma unroll
    for (int t = 0; t < TT; ++t) l += __expf(sc[t] - m);

    float4 acc = make_float4(0.f, 0.f, 0.f, 0.f);
#pragma unroll
    for (int j = 0; j < 16; ++j) {
        float wt = __expf(sc[w * 16 + j] - m);
        acc.x += wt * xv[j].x;
        acc.y += wt * xv[j].y;
        acc.z += wt * xv[j].z;
        acc.w += wt * xv[j].w;
    }
    *reinterpret_cast<float4*>(&part[w][4 * lane]) = acc;
    __syncthreads();

    float v = part[0][tid] + part[1][tid] + part[2][tid] + part[3][tid];
    out_row[tid] = v / l;
}

__global__ __launch_bounds__(256) void fused_kernel(const float* __restrict__ x,
                                                    const float* __restrict__ W,
                                                    float* __restrict__ out) {
    const int row = blockIdx.x;
    const int tid = threadIdx.x;
    const int lane = tid & 63;
    const float* xt = x + (size_t)row * (TT * FF);

    __shared__ float q[FF];
    __shared__ float wqs[FF];
    if (tid < 64) {
        float4 v = *reinterpret_cast<const float4*>(xt + (size_t)(TT - 1) * FF + tid * 4);
        *reinterpret_cast<float4*>(&q[tid * 4]) = v;
    }
    __syncthreads();

    float a = 0.f;
    const float* wrow = W + (size_t)tid * FF;
    for (int d0 = 0; d0 < FF; d0 += 4) {
        float4 wv = *reinterpret_cast<const float4*>(wrow + d0);
        float4 qv = *reinterpret_cast<const float4*>(&q[d0]);
        a += wv.x * qv.x + wv.y * qv.y + wv.z * qv.z + wv.w * qv.w;
    }
    wqs[tid] = a;
    __syncthreads();

    float4 wqv = *reinterpret_cast<const float4*>(&wqs[4 * lane]);
    attn_row_fb(xt, wqv, out + (size_t)row * FF, tid);
}

extern "C" void kernel_launch(void* const* d_in, const int* in_sizes, int n_in,
                              void* d_out, int out_size, void* d_ws, size_t ws_size,
                              hipStream_t stream) {
    (void)n_in; (void)out_size;
    const float* x = (const float*)d_in[0];
    const float* W = (const float*)d_in[1];
    float* out = (float*)d_out;

    const int rows = in_sizes[0] / (TT * FF);   // 8192
    const size_t wq_bytes = (size_t)rows * FF * sizeof(float);

    if (ws_size >= wq_bytes) {
        float* wq = (float*)d_ws;
        wq_kernel<<<rows / QR, 256, 0, stream>>>(x, W, wq);
        attn_kernel8<<<rows, 512, 0, stream>>>(x, wq, out);
    } else {
        fused_kernel<<<rows, 256, 0, stream>>>(x, W, out);
    }
}

// Round 7
// 128.640 us; speedup vs baseline: 1.1686x; 1.1016x over previous
//
#include <hip/hip_runtime.h>
#include <hip/hip_bf16.h>
#include <math.h>

// x: (B=16, S=512, T=64, F=256) fp32.  rows = B*S = 8192, tile = T*F = 16384 floats.
// out[row][f] = sum_t softmax_t( sum_f' x[row][t][f'] * wq[row][f'] ) * x[row][t][f]
// wq[row][f]  = sum_d W[f][d] * x[row][63][d]

#define TT 64
#define FF 256
#define KC 64   // K-chunk in wq GEMM
#define PAD 68  // LDS row pitch (floats): multiple of 4 (16B-aligned b128), 68%32=4 -> 2-way max

// ---------------- kernel 1: wq = q @ W^T as a register-tiled GEMM ----------------
// M=8192 (rows), N=256 (f), K=256 (d). Block: 64x64 tile, 256 threads, 4x4 per thread.
// LDS stores both operands k-major ([k][r], [k][f]) so inner-loop reads are b128.
__global__ __launch_bounds__(256) void wq_gemm(const float* __restrict__ x,
                                               const float* __restrict__ W,
                                               float* __restrict__ wq) {
    __shared__ float qs[KC][PAD];   // qs[k][r]  r = row within tile
    __shared__ float ws[KC][PAD];   // ws[k][f]  f = feature within tile

    const int tid = threadIdx.x;
    const int r0 = (blockIdx.x >> 2) * 64;   // row-tile origin
    const int f0 = (blockIdx.x & 3) * 64;    // f-tile origin

    // compute mapping: 16x16 threads, 4x4 outputs each
    const int tf = tid & 15;        // f-group: cols f0 + 4*tf .. +3
    const int tr = tid >> 4;        // r-group: rows r0 + 4*tr .. +3

    // staging mapping: 16 k-float4 x 16 rows per pass, 4 passes
    const int sc = tid & 15;        // k-chunk float4 index 0..15 (covers KC=64)
    const int sr = tid >> 4;        // row 0..15 (+16p)

    float4 acc[4];
#pragma unroll
    for (int j = 0; j < 4; ++j) acc[j] = make_float4(0.f, 0.f, 0.f, 0.f);

    for (int k0 = 0; k0 < FF; k0 += KC) {
        __syncthreads();   // protect LDS from previous chunk's readers
#pragma unroll
        for (int p = 0; p < 4; ++p) {
            int r = sr + 16 * p;
            // q row r: last timestep of tile-row r0+r
            float4 v = *reinterpret_cast<const float4*>(
                x + (size_t)(r0 + r) * (TT * FF) + (size_t)(TT - 1) * FF + k0 + 4 * sc);
            qs[4 * sc + 0][r] = v.x;
            qs[4 * sc + 1][r] = v.y;
            qs[4 * sc + 2][r] = v.z;
            qs[4 * sc + 3][r] = v.w;
            // W row f0+r (f-rows staged by the same index)
            float4 u = *reinterpret_cast<const float4*>(
                W + (size_t)(f0 + r) * FF + k0 + 4 * sc);
            ws[4 * sc + 0][r] = u.x;
            ws[4 * sc + 1][r] = u.y;
            ws[4 * sc + 2][r] = u.z;
            ws[4 * sc + 3][r] = u.w;
        }
        __syncthreads();

#pragma unroll
        for (int k = 0; k < KC; ++k) {
            float4 qv = *reinterpret_cast<const float4*>(&qs[k][4 * tr]);
            float4 wv = *reinterpret_cast<const float4*>(&ws[k][4 * tf]);
            acc[0].x = fmaf(qv.x, wv.x, acc[0].x);
            acc[0].y = fmaf(qv.x, wv.y, acc[0].y);
            acc[0].z = fmaf(qv.x, wv.z, acc[0].z);
            acc[0].w = fmaf(qv.x, wv.w, acc[0].w);
            acc[1].x = fmaf(qv.y, wv.x, acc[1].x);
            acc[1].y = fmaf(qv.y, wv.y, acc[1].y);
            acc[1].z = fmaf(qv.y, wv.z, acc[1].z);
            acc[1].w = fmaf(qv.y, wv.w, acc[1].w);
            acc[2].x = fmaf(qv.z, wv.x, acc[2].x);
            acc[2].y = fmaf(qv.z, wv.y, acc[2].y);
            acc[2].z = fmaf(qv.z, wv.z, acc[2].z);
            acc[2].w = fmaf(qv.z, wv.w, acc[2].w);
            acc[3].x = fmaf(qv.w, wv.x, acc[3].x);
            acc[3].y = fmaf(qv.w, wv.y, acc[3].y);
            acc[3].z = fmaf(qv.w, wv.z, acc[3].z);
            acc[3].w = fmaf(qv.w, wv.w, acc[3].w);
        }
    }

#pragma unroll
    for (int j = 0; j < 4; ++j)
        *reinterpret_cast<float4*>(
            wq + (size_t)(r0 + 4 * tr + j) * FF + f0 + 4 * tf) = acc[j];
}

// ---------------- kernel 2: attention, 512 threads = 8 waves x 8 t-rows (R6 best, verbatim) ----------------
__global__ __launch_bounds__(512, 4) void attn_kernel8(const float* __restrict__ x,
                                                       const float* __restrict__ wq,
                                                       float* __restrict__ out) {
    const int tid  = threadIdx.x;
    const int lane = tid & 63;
    const int w    = tid >> 6;        // wave 0..7, owns t = 8w .. 8w+7
    const int row  = blockIdx.x;
    const float* xt = x + (size_t)row * (TT * FF);

    __shared__ float sc[TT];
    __shared__ float mbuf[8];
    __shared__ float lbuf[8];
    __shared__ float part[8][FF];

    float4 wqv = *reinterpret_cast<const float4*>(wq + (size_t)row * FF + 4 * lane);

    float4 xv[8];
#pragma unroll
    for (int j = 0; j < 8; ++j)
        xv[j] = *reinterpret_cast<const float4*>(
            xt + (size_t)(w * 8 + j) * FF + 4 * lane);

    float p[8];
#pragma unroll
    for (int j = 0; j < 8; ++j)
        p[j] = xv[j].x * wqv.x + xv[j].y * wqv.y + xv[j].z * wqv.z + xv[j].w * wqv.w;

    const bool b5 = (lane & 32) != 0;
    const bool b4 = (lane & 16) != 0;
    const bool b3 = (lane & 8) != 0;

    float s4[4];
#pragma unroll
    for (int j = 0; j < 4; ++j) {
        float send = b5 ? p[j] : p[j + 4];
        float recv = __shfl_xor(send, 32, 64);
        s4[j] = (b5 ? p[j + 4] : p[j]) + recv;
    }
    float s2[2];
#pragma unroll
    for (int j = 0; j < 2; ++j) {
        float send = b4 ? s4[j] : s4[j + 2];
        float recv = __shfl_xor(send, 16, 64);
        s2[j] = (b4 ? s4[j + 2] : s4[j]) + recv;
    }
    {
        float send = b3 ? s2[0] : s2[1];
        float recv = __shfl_xor(send, 8, 64);
        s2[0] = (b3 ? s2[1] : s2[0]) + recv;
    }
    float y = s2[0];
    y += __shfl_xor(y, 4, 64);
    y += __shfl_xor(y, 2, 64);
    y += __shfl_xor(y, 1, 64);

    float mw = y;
    mw = fmaxf(mw, __shfl_xor(mw, 8, 64));
    mw = fmaxf(mw, __shfl_xor(mw, 16, 64));
    mw = fmaxf(mw, __shfl_xor(mw, 32, 64));

    if ((lane & 7) == 0) sc[w * 8 + (lane >> 3)] = y;
    if (lane == 0) mbuf[w] = mw;
    __syncthreads();

    float m = mbuf[0];
#pragma unroll
    for (int i = 1; i < 8; ++i) m = fmaxf(m, mbuf[i]);

    float wt[8];
    float lw = 0.f;
#pragma unroll
    for (int j = 0; j < 8; ++j) {
        wt[j] = __expf(sc[w * 8 + j] - m);
        lw += wt[j];
    }

    float4 acc = make_float4(0.f, 0.f, 0.f, 0.f);
#pragma unroll
    for (int j = 0; j < 8; ++j) {
        acc.x += wt[j] * xv[j].x;
        acc.y += wt[j] * xv[j].y;
        acc.z += wt[j] * xv[j].z;
        acc.w += wt[j] * xv[j].w;
    }
    *reinterpret_cast<float4*>(&part[w][4 * lane]) = acc;
    if (lane == 0) lbuf[w] = lw;
    __syncthreads();

    if (tid < FF) {
        float l = 0.f;
#pragma unroll
        for (int i = 0; i < 8; ++i) l += lbuf[i];
        float v = 0.f;
#pragma unroll
        for (int i = 0; i < 8; ++i) v += part[i][tid];
        out[(size_t)row * FF + tid] = v / l;
    }
}

// ---------------- fallback: fully fused (only if ws too small) ----------------
__device__ __forceinline__ void attn_row_fb(const float* __restrict__ xt,
                                            float4 wqv,
                                            float* __restrict__ out_row,
                                            int tid) {
    const int lane = tid & 63;
    const int w    = tid >> 6;

    __shared__ float sc[TT];
    __shared__ float part[4][FF];

    float4 xv[16];
#pragma unroll
    for (int j = 0; j < 16; ++j)
        xv[j] = *reinterpret_cast<const float4*>(xt + (size_t)(w * 16 + j) * FF + 4 * lane);

#pragma unroll
    for (int j = 0; j < 16; ++j) {
        float s = xv[j].x * wqv.x + xv[j].y * wqv.y + xv[j].z * wqv.z + xv[j].w * wqv.w;
#pragma unroll
        for (int off = 32; off > 0; off >>= 1)
            s += __shfl_xor(s, off, 64);
        if (lane == 0) sc[w * 16 + j] = s;
    }
    __syncthreads();

    float m = -INFINITY;
#pragma unroll
    for (int t = 0; t < TT; ++t) m = fmaxf(m, sc[t]);
    float l = 0.f;
#pragma unroll
    for (int t = 0; t < TT; ++t) l += __expf(sc[t] - m);

    float4 acc = make_float4(0.f, 0.f, 0.f, 0.f);
#pragma unroll
    for (int j = 0; j < 16; ++j) {
        float wt = __expf(sc[w * 16 + j] - m);
        acc.x += wt * xv[j].x;
        acc.y += wt * xv[j].y;
        acc.z += wt * xv[j].z;
        acc.w += wt * xv[j].w;
    }
    *reinterpret_cast<float4*>(&part[w][4 * lane]) = acc;
    __syncthreads();

    float v = part[0][tid] + part[1][tid] + part[2][tid] + part[3][tid];
    out_row[tid] = v / l;
}

__global__ __launch_bounds__(256) void fused_kernel(const float* __restrict__ x,
                                                    const float* __restrict__ W,
                                                    float* __restrict__ out) {
    const int row = blockIdx.x;
    const int tid = threadIdx.x;
    const int lane = tid & 63;
    const float* xt = x + (size_t)row * (TT * FF);

    __shared__ float q[FF];
    __shared__ float wqs[FF];
    if (tid < 64) {
        float4 v = *reinterpret_cast<const float4*>(xt + (size_t)(TT - 1) * FF + tid * 4);
        *reinterpret_cast<float4*>(&q[tid * 4]) = v;
    }
    __syncthreads();

    float a = 0.f;
    const float* wrow = W + (size_t)tid * FF;
    for (int d0 = 0; d0 < FF; d0 += 4) {
        float4 wv = *reinterpret_cast<const float4*>(wrow + d0);
        float4 qv = *reinterpret_cast<const float4*>(&q[d0]);
        a += wv.x * qv.x + wv.y * qv.y + wv.z * qv.z + wv.w * qv.w;
    }
    wqs[tid] = a;
    __syncthreads();

    float4 wqv = *reinterpret_cast<const float4*>(&wqs[4 * lane]);
    attn_row_fb(xt, wqv, out + (size_t)row * FF, tid);
}

extern "C" void kernel_launch(void* const* d_in, const int* in_sizes, int n_in,
                              void* d_out, int out_size, void* d_ws, size_t ws_size,
                              hipStream_t stream) {
    (void)n_in; (void)out_size;
    const float* x = (const float*)d_in[0];
    const float* W = (const float*)d_in[1];
    float* out = (float*)d_out;

    const int rows = in_sizes[0] / (TT * FF);   // 8192
    const size_t wq_bytes = (size_t)rows * FF * sizeof(float);

    if (ws_size >= wq_bytes) {
        float* wq = (float*)d_ws;
        wq_gemm<<<(rows / 64) * 4, 256, 0, stream>>>(x, W, wq);
        attn_kernel8<<<rows, 512, 0, stream>>>(x, wq, out);
    } else {
        fused_kernel<<<rows, 256, 0, stream>>>(x, W, out);
    }
}

// Round 8
// 118.513 us; speedup vs baseline: 1.2685x; 1.0854x over previous
//
#include <hip/hip_runtime.h>
#include <hip/hip_bf16.h>
#include <math.h>

// x: (B=16, S=512, T=64, F=256) fp32.  rows = B*S = 8192, tile = T*F = 16384 floats.
// out[row][f] = sum_t softmax_t( sum_f' x[row][t][f'] * wq[row][f'] ) * x[row][t][f]
// wq[row][f]  = sum_d W[f][d] * x[row][63][d]

#define TT 64
#define FF 256
#define KC 64   // K-chunk in wq GEMM
#define PAD 68  // LDS row pitch (floats): multiple of 4 (16B-aligned b128), 68%32=4 -> 2-way max

typedef float v4f __attribute__((ext_vector_type(4)));

// non-temporal float4 load (evict-first: x is streamed once, don't thrash L2/L3)
__device__ __forceinline__ float4 ntload4(const float* p) {
    v4f t = __builtin_nontemporal_load(reinterpret_cast<const v4f*>(p));
    float4 r; r.x = t.x; r.y = t.y; r.z = t.z; r.w = t.w;
    return r;
}

// ---------------- kernel 1: wq = q @ W^T register-tiled GEMM (R7 measured-best, verbatim) ----------------
__global__ __launch_bounds__(256) void wq_gemm(const float* __restrict__ x,
                                               const float* __restrict__ W,
                                               float* __restrict__ wq) {
    __shared__ float qs[KC][PAD];   // qs[k][r]
    __shared__ float ws[KC][PAD];   // ws[k][f]

    const int tid = threadIdx.x;
    const int r0 = (blockIdx.x >> 2) * 64;
    const int f0 = (blockIdx.x & 3) * 64;

    const int tf = tid & 15;
    const int tr = tid >> 4;

    const int sc = tid & 15;
    const int sr = tid >> 4;

    float4 acc[4];
#pragma unroll
    for (int j = 0; j < 4; ++j) acc[j] = make_float4(0.f, 0.f, 0.f, 0.f);

    for (int k0 = 0; k0 < FF; k0 += KC) {
        __syncthreads();
#pragma unroll
        for (int p = 0; p < 4; ++p) {
            int r = sr + 16 * p;
            float4 v = *reinterpret_cast<const float4*>(
                x + (size_t)(r0 + r) * (TT * FF) + (size_t)(TT - 1) * FF + k0 + 4 * sc);
            qs[4 * sc + 0][r] = v.x;
            qs[4 * sc + 1][r] = v.y;
            qs[4 * sc + 2][r] = v.z;
            qs[4 * sc + 3][r] = v.w;
            float4 u = *reinterpret_cast<const float4*>(
                W + (size_t)(f0 + r) * FF + k0 + 4 * sc);
            ws[4 * sc + 0][r] = u.x;
            ws[4 * sc + 1][r] = u.y;
            ws[4 * sc + 2][r] = u.z;
            ws[4 * sc + 3][r] = u.w;
        }
        __syncthreads();

#pragma unroll
        for (int k = 0; k < KC; ++k) {
            float4 qv = *reinterpret_cast<const float4*>(&qs[k][4 * tr]);
            float4 wv = *reinterpret_cast<const float4*>(&ws[k][4 * tf]);
            acc[0].x = fmaf(qv.x, wv.x, acc[0].x);
            acc[0].y = fmaf(qv.x, wv.y, acc[0].y);
            acc[0].z = fmaf(qv.x, wv.z, acc[0].z);
            acc[0].w = fmaf(qv.x, wv.w, acc[0].w);
            acc[1].x = fmaf(qv.y, wv.x, acc[1].x);
            acc[1].y = fmaf(qv.y, wv.y, acc[1].y);
            acc[1].z = fmaf(qv.y, wv.z, acc[1].z);
            acc[1].w = fmaf(qv.y, wv.w, acc[1].w);
            acc[2].x = fmaf(qv.z, wv.x, acc[2].x);
            acc[2].y = fmaf(qv.z, wv.y, acc[2].y);
            acc[2].z = fmaf(qv.z, wv.z, acc[2].z);
            acc[2].w = fmaf(qv.z, wv.w, acc[2].w);
            acc[3].x = fmaf(qv.w, wv.x, acc[3].x);
            acc[3].y = fmaf(qv.w, wv.y, acc[3].y);
            acc[3].z = fmaf(qv.w, wv.z, acc[3].z);
            acc[3].w = fmaf(qv.w, wv.w, acc[3].w);
        }
    }

#pragma unroll
    for (int j = 0; j < 4; ++j)
        *reinterpret_cast<float4*>(
            wq + (size_t)(r0 + 4 * tr + j) * FF + f0 + 4 * tf) = acc[j];
}

// ---------------- kernel 2: attention, 512 threads = 8 waves x 8 t-rows + NT x-loads ----------------
__global__ __launch_bounds__(512, 4) void attn_kernel8(const float* __restrict__ x,
                                                       const float* __restrict__ wq,
                                                       float* __restrict__ out) {
    const int tid  = threadIdx.x;
    const int lane = tid & 63;
    const int w    = tid >> 6;        // wave 0..7, owns t = 8w .. 8w+7
    const int row  = blockIdx.x;
    const float* xt = x + (size_t)row * (TT * FF);

    __shared__ float sc[TT];
    __shared__ float mbuf[8];
    __shared__ float lbuf[8];
    __shared__ float part[8][FF];

    float4 wqv = *reinterpret_cast<const float4*>(wq + (size_t)row * FF + 4 * lane);

    // 8 rows in registers, NT (x is never re-read: don't fill L2/L3)
    float4 xv[8];
#pragma unroll
    for (int j = 0; j < 8; ++j)
        xv[j] = ntload4(xt + (size_t)(w * 8 + j) * FF + 4 * lane);

    float p[8];
#pragma unroll
    for (int j = 0; j < 8; ++j)
        p[j] = xv[j].x * wqv.x + xv[j].y * wqv.y + xv[j].z * wqv.z + xv[j].w * wqv.w;

    const bool b5 = (lane & 32) != 0;
    const bool b4 = (lane & 16) != 0;
    const bool b3 = (lane & 8) != 0;

    float s4[4];
#pragma unroll
    for (int j = 0; j < 4; ++j) {
        float send = b5 ? p[j] : p[j + 4];
        float recv = __shfl_xor(send, 32, 64);
        s4[j] = (b5 ? p[j + 4] : p[j]) + recv;
    }
    float s2[2];
#pragma unroll
    for (int j = 0; j < 2; ++j) {
        float send = b4 ? s4[j] : s4[j + 2];
        float recv = __shfl_xor(send, 16, 64);
        s2[j] = (b4 ? s4[j + 2] : s4[j]) + recv;
    }
    {
        float send = b3 ? s2[0] : s2[1];
        float recv = __shfl_xor(send, 8, 64);
        s2[0] = (b3 ? s2[1] : s2[0]) + recv;
    }
    float y = s2[0];
    y += __shfl_xor(y, 4, 64);
    y += __shfl_xor(y, 2, 64);
    y += __shfl_xor(y, 1, 64);

    float mw = y;
    mw = fmaxf(mw, __shfl_xor(mw, 8, 64));
    mw = fmaxf(mw, __shfl_xor(mw, 16, 64));
    mw = fmaxf(mw, __shfl_xor(mw, 32, 64));

    if ((lane & 7) == 0) sc[w * 8 + (lane >> 3)] = y;
    if (lane == 0) mbuf[w] = mw;
    __syncthreads();

    float m = mbuf[0];
#pragma unroll
    for (int i = 1; i < 8; ++i) m = fmaxf(m, mbuf[i]);

    float wt[8];
    float lw = 0.f;
#pragma unroll
    for (int j = 0; j < 8; ++j) {
        wt[j] = __expf(sc[w * 8 + j] - m);
        lw += wt[j];
    }

    float4 acc = make_float4(0.f, 0.f, 0.f, 0.f);
#pragma unroll
    for (int j = 0; j < 8; ++j) {
        acc.x += wt[j] * xv[j].x;
        acc.y += wt[j] * xv[j].y;
        acc.z += wt[j] * xv[j].z;
        acc.w += wt[j] * xv[j].w;
    }
    *reinterpret_cast<float4*>(&part[w][4 * lane]) = acc;
    if (lane == 0) lbuf[w] = lw;
    __syncthreads();

    if (tid < FF) {
        float l = 0.f;
#pragma unroll
        for (int i = 0; i < 8; ++i) l += lbuf[i];
        float v = 0.f;
#pragma unroll
        for (int i = 0; i < 8; ++i) v += part[i][tid];
        __builtin_nontemporal_store(v / l, out + (size_t)row * FF + tid);
    }
}

// ---------------- fallback: fully fused (only if ws too small) ----------------
__device__ __forceinline__ void attn_row_fb(const float* __restrict__ xt,
                                            float4 wqv,
                                            float* __restrict__ out_row,
                                            int tid) {
    const int lane = tid & 63;
    const int w    = tid >> 6;

    __shared__ float sc[TT];
    __shared__ float part[4][FF];

    float4 xv[16];
#pragma unroll
    for (int j = 0; j < 16; ++j)
        xv[j] = *reinterpret_cast<const float4*>(xt + (size_t)(w * 16 + j) * FF + 4 * lane);

#pragma unroll
    for (int j = 0; j < 16; ++j) {
        float s = xv[j].x * wqv.x + xv[j].y * wqv.y + xv[j].z * wqv.z + xv[j].w * wqv.w;
#pragma unroll
        for (int off = 32; off > 0; off >>= 1)
            s += __shfl_xor(s, off, 64);
        if (lane == 0) sc[w * 16 + j] = s;
    }
    __syncthreads();

    float m = -INFINITY;
#pragma unroll
    for (int t = 0; t < TT; ++t) m = fmaxf(m, sc[t]);
    float l = 0.f;
#pragma unroll
    for (int t = 0; t < TT; ++t) l += __expf(sc[t] - m);

    float4 acc = make_float4(0.f, 0.f, 0.f, 0.f);
#pragma unroll
    for (int j = 0; j < 16; ++j) {
        float wt = __expf(sc[w * 16 + j] - m);
        acc.x += wt * xv[j].x;
        acc.y += wt * xv[j].y;
        acc.z += wt * xv[j].z;
        acc.w += wt * xv[j].w;
    }
    *reinterpret_cast<float4*>(&part[w][4 * lane]) = acc;
    __syncthreads();

    float v = part[0][tid] + part[1][tid] + part[2][tid] + part[3][tid];
    out_row[tid] = v / l;
}

__global__ __launch_bounds__(256) void fused_kernel(const float* __restrict__ x,
                                                    const float* __restrict__ W,
                                                    float* __restrict__ out) {
    const int row = blockIdx.x;
    const int tid = threadIdx.x;
    const int lane = tid & 63;
    const float* xt = x + (size_t)row * (TT * FF);

    __shared__ float q[FF];
    __shared__ float wqs[FF];
    if (tid < 64) {
        float4 v = *reinterpret_cast<const float4*>(xt + (size_t)(TT - 1) * FF + tid * 4);
        *reinterpret_cast<float4*>(&q[tid * 4]) = v;
    }
    __syncthreads();

    float a = 0.f;
    const float* wrow = W + (size_t)tid * FF;
    for (int d0 = 0; d0 < FF; d0 += 4) {
        float4 wv = *reinterpret_cast<const float4*>(wrow + d0);
        float4 qv = *reinterpret_cast<const float4*>(&q[d0]);
        a += wv.x * qv.x + wv.y * qv.y + wv.z * qv.z + wv.w * qv.w;
    }
    wqs[tid] = a;
    __syncthreads();

    float4 wqv = *reinterpret_cast<const float4*>(&wqs[4 * lane]);
    attn_row_fb(xt, wqv, out + (size_t)row * FF, tid);
}

extern "C" void kernel_launch(void* const* d_in, const int* in_sizes, int n_in,
                              void* d_out, int out_size, void* d_ws, size_t ws_size,
                              hipStream_t stream) {
    (void)n_in; (void)out_size;
    const float* x = (const float*)d_in[0];
    const float* W = (const float*)d_in[1];
    float* out = (float*)d_out;

    const int rows = in_sizes[0] / (TT * FF);   // 8192
    const size_t wq_bytes = (size_t)rows * FF * sizeof(float);

    if (ws_size >= wq_bytes) {
        float* wq = (float*)d_ws;
        wq_gemm<<<(rows / 64) * 4, 256, 0, stream>>>(x, W, wq);
        attn_kernel8<<<rows, 512, 0, stream>>>(x, wq, out);
    } else {
        fused_kernel<<<rows, 256, 0, stream>>>(x, W, out);
    }
}

// Round 9
// 113.431 us; speedup vs baseline: 1.3253x; 1.0448x over previous
//
#include <hip/hip_runtime.h>
#include <hip/hip_bf16.h>
#include <math.h>

// x: (B=16, S=512, T=64, F=256) fp32.  rows = B*S = 8192, tile = T*F = 16384 floats.
// out[row][f] = sum_t softmax_t( sum_f' x[row][t][f'] * wq[row][f'] ) * x[row][t][f]
// wq[row][f]  = sum_d W[f][d] * x[row][63][d]

#define TT 64
#define FF 256
#define KC 64   // K-chunk in wq GEMM
#define PAD 68  // LDS row pitch (floats)

typedef float v4f __attribute__((ext_vector_type(4)));

__device__ __forceinline__ float4 ntload4(const float* p) {
    v4f t = __builtin_nontemporal_load(reinterpret_cast<const v4f*>(p));
    float4 r; r.x = t.x; r.y = t.y; r.z = t.z; r.w = t.w;
    return r;
}

// ---------------- kernel 1: wq = q @ W^T register-tiled GEMM (R7/R8 measured-best, verbatim) ----------------
__global__ __launch_bounds__(256) void wq_gemm(const float* __restrict__ x,
                                               const float* __restrict__ W,
                                               float* __restrict__ wq) {
    __shared__ float qs[KC][PAD];
    __shared__ float ws[KC][PAD];

    const int tid = threadIdx.x;
    const int r0 = (blockIdx.x >> 2) * 64;
    const int f0 = (blockIdx.x & 3) * 64;

    const int tf = tid & 15;
    const int tr = tid >> 4;

    const int sc = tid & 15;
    const int sr = tid >> 4;

    float4 acc[4];
#pragma unroll
    for (int j = 0; j < 4; ++j) acc[j] = make_float4(0.f, 0.f, 0.f, 0.f);

    for (int k0 = 0; k0 < FF; k0 += KC) {
        __syncthreads();
#pragma unroll
        for (int p = 0; p < 4; ++p) {
            int r = sr + 16 * p;
            float4 v = *reinterpret_cast<const float4*>(
                x + (size_t)(r0 + r) * (TT * FF) + (size_t)(TT - 1) * FF + k0 + 4 * sc);
            qs[4 * sc + 0][r] = v.x;
            qs[4 * sc + 1][r] = v.y;
            qs[4 * sc + 2][r] = v.z;
            qs[4 * sc + 3][r] = v.w;
            float4 u = *reinterpret_cast<const float4*>(
                W + (size_t)(f0 + r) * FF + k0 + 4 * sc);
            ws[4 * sc + 0][r] = u.x;
            ws[4 * sc + 1][r] = u.y;
            ws[4 * sc + 2][r] = u.z;
            ws[4 * sc + 3][r] = u.w;
        }
        __syncthreads();

#pragma unroll
        for (int k = 0; k < KC; ++k) {
            float4 qv = *reinterpret_cast<const float4*>(&qs[k][4 * tr]);
            float4 wv = *reinterpret_cast<const float4*>(&ws[k][4 * tf]);
            acc[0].x = fmaf(qv.x, wv.x, acc[0].x);
            acc[0].y = fmaf(qv.x, wv.y, acc[0].y);
            acc[0].z = fmaf(qv.x, wv.z, acc[0].z);
            acc[0].w = fmaf(qv.x, wv.w, acc[0].w);
            acc[1].x = fmaf(qv.y, wv.x, acc[1].x);
            acc[1].y = fmaf(qv.y, wv.y, acc[1].y);
            acc[1].z = fmaf(qv.y, wv.z, acc[1].z);
            acc[1].w = fmaf(qv.y, wv.w, acc[1].w);
            acc[2].x = fmaf(qv.z, wv.x, acc[2].x);
            acc[2].y = fmaf(qv.z, wv.y, acc[2].y);
            acc[2].z = fmaf(qv.z, wv.z, acc[2].z);
            acc[2].w = fmaf(qv.z, wv.w, acc[2].w);
            acc[3].x = fmaf(qv.w, wv.x, acc[3].x);
            acc[3].y = fmaf(qv.w, wv.y, acc[3].y);
            acc[3].z = fmaf(qv.w, wv.z, acc[3].z);
            acc[3].w = fmaf(qv.w, wv.w, acc[3].w);
        }
    }

#pragma unroll
    for (int j = 0; j < 4; ++j)
        *reinterpret_cast<float4*>(
            wq + (size_t)(r0 + 4 * tr + j) * FF + f0 + 4 * tf) = acc[j];
}

// ---------------- kernel 2: attention, 1024 threads = 16 waves x 4 t-rows ----------------
// Target: <=64 VGPR (xv[4]=16) -> 32 waves/CU (2 blocks) to saturate VMEM issue.
__global__ __launch_bounds__(1024, 8) void attn_kernel4(const float* __restrict__ x,
                                                        const float* __restrict__ wq,
                                                        float* __restrict__ out) {
    const int tid  = threadIdx.x;
    const int lane = tid & 63;
    const int w    = tid >> 6;        // wave 0..15, owns t = 4w .. 4w+3
    const int row  = blockIdx.x;
    const float* xt = x + (size_t)row * (TT * FF);

    __shared__ float sc[TT];
    __shared__ float mbuf[16];
    __shared__ float lbuf[16];
    __shared__ float part[16][FF];

    float4 wqv = *reinterpret_cast<const float4*>(wq + (size_t)row * FF + 4 * lane);

    // 4 rows in registers, NT (x never re-read: evict-first)
    float4 xv[4];
#pragma unroll
    for (int j = 0; j < 4; ++j)
        xv[j] = ntload4(xt + (size_t)(w * 4 + j) * FF + 4 * lane);

    float p[4];
#pragma unroll
    for (int j = 0; j < 4; ++j)
        p[j] = xv[j].x * wqv.x + xv[j].y * wqv.y + xv[j].z * wqv.z + xv[j].w * wqv.w;

    // fold-reduce: 4 row-sums across 64 lanes in 6 shuffles
    const bool b5 = (lane & 32) != 0;
    const bool b4 = (lane & 16) != 0;

    float s2[2];
#pragma unroll
    for (int j = 0; j < 2; ++j) {
        float send = b5 ? p[j] : p[j + 2];
        float recv = __shfl_xor(send, 32, 64);
        s2[j] = (b5 ? p[j + 2] : p[j]) + recv;      // row = 2*b5 + j
    }
    float y;
    {
        float send = b4 ? s2[0] : s2[1];
        float recv = __shfl_xor(send, 16, 64);
        y = (b4 ? s2[1] : s2[0]) + recv;            // row = lane>>4
    }
    y += __shfl_xor(y, 8, 64);
    y += __shfl_xor(y, 4, 64);
    y += __shfl_xor(y, 2, 64);
    y += __shfl_xor(y, 1, 64);                      // full score of row lane>>4

    // wave max over its 4 rows (fold lane bits 4..5)
    float mw = y;
    mw = fmaxf(mw, __shfl_xor(mw, 16, 64));
    mw = fmaxf(mw, __shfl_xor(mw, 32, 64));

    if ((lane & 15) == 0) sc[w * 4 + (lane >> 4)] = y;
    if (lane == 0) mbuf[w] = mw;
    __syncthreads();

    float m = mbuf[0];
#pragma unroll
    for (int i = 1; i < 16; ++i) m = fmaxf(m, mbuf[i]);

    float wt[4];
    float lw = 0.f;
#pragma unroll
    for (int j = 0; j < 4; ++j) {
        wt[j] = __expf(sc[w * 4 + j] - m);
        lw += wt[j];
    }

    float4 acc = make_float4(0.f, 0.f, 0.f, 0.f);
#pragma unroll
    for (int j = 0; j < 4; ++j) {
        acc.x += wt[j] * xv[j].x;
        acc.y += wt[j] * xv[j].y;
        acc.z += wt[j] * xv[j].z;
        acc.w += wt[j] * xv[j].w;
    }
    *reinterpret_cast<float4*>(&part[w][4 * lane]) = acc;
    if (lane == 0) lbuf[w] = lw;
    __syncthreads();

    if (tid < FF) {
        float l = 0.f;
#pragma unroll
        for (int i = 0; i < 16; ++i) l += lbuf[i];
        float v = 0.f;
#pragma unroll
        for (int i = 0; i < 16; ++i) v += part[i][tid];
        __builtin_nontemporal_store(v / l, out + (size_t)row * FF + tid);
    }
}

// ---------------- fallback: fully fused (only if ws too small) ----------------
__device__ __forceinline__ void attn_row_fb(const float* __restrict__ xt,
                                            float4 wqv,
                                            float* __restrict__ out_row,
                                            int tid) {
    const int lane = tid & 63;
    const int w    = tid >> 6;

    __shared__ float sc[TT];
    __shared__ float part[4][FF];

    float4 xv[16];
#pragma unroll
    for (int j = 0; j < 16; ++j)
        xv[j] = *reinterpret_cast<const float4*>(xt + (size_t)(w * 16 + j) * FF + 4 * lane);

#pragma unroll
    for (int j = 0; j < 16; ++j) {
        float s = xv[j].x * wqv.x + xv[j].y * wqv.y + xv[j].z * wqv.z + xv[j].w * wqv.w;
#pragma unroll
        for (int off = 32; off > 0; off >>= 1)
            s += __shfl_xor(s, off, 64);
        if (lane == 0) sc[w * 16 + j] = s;
    }
    __syncthreads();

    float m = -INFINITY;
#pragma unroll
    for (int t = 0; t < TT; ++t) m = fmaxf(m, sc[t]);
    float l = 0.f;
#pragma unroll
    for (int t = 0; t < TT; ++t) l += __expf(sc[t] - m);

    float4 acc = make_float4(0.f, 0.f, 0.f, 0.f);
#pragma unroll
    for (int j = 0; j < 16; ++j) {
        float wt = __expf(sc[w * 16 + j] - m);
        acc.x += wt * xv[j].x;
        acc.y += wt * xv[j].y;
        acc.z += wt * xv[j].z;
        acc.w += wt * xv[j].w;
    }
    *reinterpret_cast<float4*>(&part[w][4 * lane]) = acc;
    __syncthreads();

    float v = part[0][tid] + part[1][tid] + part[2][tid] + part[3][tid];
    out_row[tid] = v / l;
}

__global__ __launch_bounds__(256) void fused_kernel(const float* __restrict__ x,
                                                    const float* __restrict__ W,
                                                    float* __restrict__ out) {
    const int row = blockIdx.x;
    const int tid = threadIdx.x;
    const int lane = tid & 63;
    const float* xt = x + (size_t)row * (TT * FF);

    __shared__ float q[FF];
    __shared__ float wqs[FF];
    if (tid < 64) {
        float4 v = *reinterpret_cast<const float4*>(xt + (size_t)(TT - 1) * FF + tid * 4);
        *reinterpret_cast<float4*>(&q[tid * 4]) = v;
    }
    __syncthreads();

    float a = 0.f;
    const float* wrow = W + (size_t)tid * FF;
    for (int d0 = 0; d0 < FF; d0 += 4) {
        float4 wv = *reinterpret_cast<const float4*>(wrow + d0);
        float4 qv = *reinterpret_cast<const float4*>(&q[d0]);
        a += wv.x * qv.x + wv.y * qv.y + wv.z * qv.z + wv.w * qv.w;
    }
    wqs[tid] = a;
    __syncthreads();

    float4 wqv = *reinterpret_cast<const float4*>(&wqs[4 * lane]);
    attn_row_fb(xt, wqv, out + (size_t)row * FF, tid);
}

extern "C" void kernel_launch(void* const* d_in, const int* in_sizes, int n_in,
                              void* d_out, int out_size, void* d_ws, size_t ws_size,
                              hipStream_t stream) {
    (void)n_in; (void)out_size;
    const float* x = (const float*)d_in[0];
    const float* W = (const float*)d_in[1];
    float* out = (float*)d_out;

    const int rows = in_sizes[0] / (TT * FF);   // 8192
    const size_t wq_bytes = (size_t)rows * FF * sizeof(float);

    if (ws_size >= wq_bytes) {
        float* wq = (float*)d_ws;
        wq_gemm<<<(rows / 64) * 4, 256, 0, stream>>>(x, W, wq);
        attn_kernel4<<<rows, 1024, 0, stream>>>(x, wq, out);
    } else {
        fused_kernel<<<rows, 256, 0, stream>>>(x, W, out);
    }
}